// Round 6
// baseline (351.448 us; speedup 1.0000x reference)
//
#include <hip/hip_runtime.h>
#include <math.h>

// Problem constants (from reference)
#define BATCH     2
#define NLAB      256            // 64 bifs * 4 stubs
#define VOX       (192*192*192)  // 7,077,888 voxels per batch
#define VVEC      (VOX/4)        // float4 elements per batch
#define TEMP      0.2f
#define GRIDX     512            // blocks per batch (4 blocks/CU)
#define NCOPY     64             // global histogram copies per batch

// f32 packing: one atomicAdd of (STEP + fg) per voxel.
//   count = round(acc/STEP)  [s/STEP < 0.5 always], sum_fg = acc - STEP*count.
// LDS path: per-block-bin count ~27 (max ~60) -> acc <= 246k, ULP 0.016.
// Global path: per-copy-bin count ~216 (max ~300) -> acc <= 1.23M, ULP 0.0625;
// rounding RMS ~0.3/copy-bin -> ~1e-4 relative on batch-bin means. OK vs 1e-2.
#define STEP      4096.0f
#define INV_STEP  (1.0f/4096.0f)

// ---------------------------------------------------------------------------
// Kernel 1: per-batch histogram. ONE packed f32 atomic per voxel, alternating
// between the LDS atomic pipe (ds_add_f32, ~3.4cyc/lane-op, lane-serial) and
// the global/TCC atomic pipe (64 contention-spread copies) so the two halves
// run concurrently on different hardware units.
// fg = softmax(pred, ch)[1] = sigmoid(p1 - p0) since C == 2.
// ---------------------------------------------------------------------------
__global__ __launch_bounds__(256) void histo_kernel(
    const float* __restrict__ pred,     // [B,2,V]
    const float* __restrict__ labmap,   // [B,1,V]
    float* __restrict__ ws_slots,       // [B*GRIDX][256] packed per-block hist
    float* __restrict__ gcopies)        // [B*NCOPY][256] packed global copies
{
    __shared__ float s_hist[2 * NLAB];  // two copies, lane-parity selected

    const int b = blockIdx.y;
    const int tid = threadIdx.x;

    s_hist[tid] = 0.0f;          // blockDim.x == NLAB == 256
    s_hist[tid + NLAB] = 0.0f;
    __syncthreads();

    const float4* p0 = (const float4*)(pred + (size_t)b * 2 * VOX);
    const float4* p1 = (const float4*)(pred + (size_t)b * 2 * VOX + VOX);
    const float4* lm = (const float4*)(labmap + (size_t)b * VOX);

    const int copy = (tid & 1) << 8;    // LDS copy select (halves collisions)
    // global copy: spread waves across the 64 copies
    float* gbase = gcopies +
        ((size_t)b * NCOPY + ((blockIdx.x * 4 + (tid >> 6)) & (NCOPY - 1))) * NLAB;

    const int stride = GRIDX * 256;
    int it = 0;
    for (int i = blockIdx.x * 256 + tid; i < VVEC; i += stride, ++it) {
        float4 a = p0[i];   // channel 0
        float4 c = p1[i];   // channel 1
        float4 l = lm[i];   // labels (exact integers 0..255 as float)

        float fg0 = 1.0f / (1.0f + __expf(a.x - c.x));
        float fg1 = 1.0f / (1.0f + __expf(a.y - c.y));
        float fg2 = 1.0f / (1.0f + __expf(a.z - c.z));
        float fg3 = 1.0f / (1.0f + __expf(a.w - c.w));

        int l0 = ((int)(l.x + 0.5f)) & (NLAB - 1);
        int l1 = ((int)(l.y + 0.5f)) & (NLAB - 1);
        int l2 = ((int)(l.z + 0.5f)) & (NLAB - 1);
        int l3 = ((int)(l.w + 0.5f)) & (NLAB - 1);

        if (it & 1) {
            // global/TCC atomic pipe (fire-and-forget, no return)
            atomicAdd(&gbase[l0], STEP + fg0);
            atomicAdd(&gbase[l1], STEP + fg1);
            atomicAdd(&gbase[l2], STEP + fg2);
            atomicAdd(&gbase[l3], STEP + fg3);
        } else {
            // LDS atomic pipe (ds_add_f32 fast path)
            atomicAdd(&s_hist[copy + l0], STEP + fg0);
            atomicAdd(&s_hist[copy + l1], STEP + fg1);
            atomicAdd(&s_hist[copy + l2], STEP + fg2);
            atomicAdd(&s_hist[copy + l3], STEP + fg3);
        }
    }
    __syncthreads();

    // Write this block's packed LDS histogram to its private slot (coalesced,
    // unconditional -> no zeroing needed for slots).
    ws_slots[((size_t)(b * GRIDX + blockIdx.x)) * NLAB + tid] =
        s_hist[tid] + s_hist[tid + NLAB];
}

// ---------------------------------------------------------------------------
// Kernel 2: reduce slots + global copies (decode packed), then masked
// softmin -> scalar loss. Single block, 1024 threads: thread t handles bin
// (t&255), source-quarter (t>>8). Coalesced reads.
// ---------------------------------------------------------------------------
__global__ __launch_bounds__(1024) void finalize_kernel(
    const float* __restrict__ ws_slots, // [B*GRIDX][256]
    const float* __restrict__ gcopies,  // [B*NCOPY][256]
    float* __restrict__ out)            // [1] loss
{
    __shared__ float s_ps[BATCH][4][NLAB];
    __shared__ float s_pc[BATCH][4][NLAB];
    __shared__ float s_fsum[BATCH][NLAB];
    __shared__ float s_fcnt[BATCH][NLAB];

    const int tid  = threadIdx.x;
    const int bin  = tid & (NLAB - 1);
    const int part = tid >> 8;                 // 0..3
    const int perS = GRIDX / 4;                // slots per part
    const int perC = NCOPY / 4;                // copies per part

    for (int b = 0; b < BATCH; ++b) {
        float cs = 0.0f, ss = 0.0f;
        for (int s = part * perS; s < (part + 1) * perS; ++s) {
            float v = ws_slots[((size_t)(b * GRIDX + s)) * NLAB + bin];
            float c = floorf(v * INV_STEP + 0.5f);   // robust count decode
            cs += c;
            ss += v - c * STEP;
        }
        for (int s = part * perC; s < (part + 1) * perC; ++s) {
            float v = gcopies[((size_t)(b * NCOPY + s)) * NLAB + bin];
            float c = floorf(v * INV_STEP + 0.5f);
            cs += c;
            ss += v - c * STEP;
        }
        s_ps[b][part][bin] = ss;
        s_pc[b][part][bin] = cs;
    }
    __syncthreads();

    if (tid < NLAB) {
        for (int b = 0; b < BATCH; ++b) {
            s_fsum[b][tid] = (s_ps[b][0][tid] + s_ps[b][1][tid])
                           + (s_ps[b][2][tid] + s_ps[b][3][tid]);
            s_fcnt[b][tid] = (s_pc[b][0][tid] + s_pc[b][1][tid])
                           + (s_pc[b][2][tid] + s_pc[b][3][tid]);
        }
    }
    __syncthreads();

    if (tid < 64) {
        float total = 0.0f;
        float nbifs = 0.0f;
        if (tid >= 1) {  // bifs 1..63 (reference drops bif 0)
            for (int bb = 0; bb < BATCH; ++bb) {
                float means[3];
                bool  valid[3];
                int   nvalid = 0;
                for (int s = 0; s < 3; ++s) {
                    int lab = tid * 4 + 1 + s;   // stub s+1 (stub 0 dropped)
                    float cnt = s_fcnt[bb][lab];
                    float sum = s_fsum[bb][lab];
                    valid[s] = (cnt >= 1.0f);            // MIN_VOXELS = 1
                    means[s] = sum / fmaxf(cnt, 1.0f);
                    nvalid  += valid[s] ? 1 : 0;
                }
                float logits[3], m = -3e38f;
                for (int s = 0; s < 3; ++s) {
                    logits[s] = valid[s] ? (-means[s] / TEMP) : -1e9f;
                    m = fmaxf(m, logits[s]);
                }
                float e[3], se = 0.0f;
                for (int s = 0; s < 3; ++s) { e[s] = __expf(logits[s] - m); se += e[s]; }
                float score = 0.0f;
                for (int s = 0; s < 3; ++s) {
                    if (valid[s]) score += means[s] * (e[s] / se);
                }
                if (nvalid >= 2) {  // MIN_STUBS = 2
                    total += 1.0f - score;
                    nbifs += 1.0f;
                }
            }
        }
        for (int off = 32; off > 0; off >>= 1) {
            total += __shfl_down(total, off);
            nbifs += __shfl_down(nbifs, off);
        }
        if (tid == 0) {
            out[0] = (nbifs > 0.0f) ? (total / fmaxf(nbifs, 1.0f)) : 0.0f;
        }
    }
}

// ---------------------------------------------------------------------------
extern "C" void kernel_launch(void* const* d_in, const int* in_sizes, int n_in,
                              void* d_out, int out_size, void* d_ws, size_t ws_size,
                              hipStream_t stream) {
    const float* pred = (const float*)d_in[0];   // [B,C,D,H,W] fp32
    const float* lab  = (const float*)d_in[1];   // [B,1,D,H,W] fp32

    float* ws_slots = (float*)d_ws;                        // [B*GRIDX][256]
    float* gcopies  = ws_slots + (size_t)BATCH * GRIDX * NLAB; // [B*NCOPY][256]

    // Zero only the global atomic copies (slots are written unconditionally).
    hipMemsetAsync(gcopies, 0, (size_t)BATCH * NCOPY * NLAB * sizeof(float),
                   stream);

    dim3 grid(GRIDX, BATCH);
    histo_kernel<<<grid, 256, 0, stream>>>(pred, lab, ws_slots, gcopies);
    finalize_kernel<<<1, 1024, 0, stream>>>(ws_slots, gcopies, (float*)d_out);
}

// Round 7
// 234.899 us; speedup vs baseline: 1.4962x; 1.4962x over previous
//
#include <hip/hip_runtime.h>
#include <math.h>

// Problem constants (from reference)
#define BATCH     2
#define NLAB      256            // 64 bifs * 4 stubs
#define VOX       (192*192*192)  // 7,077,888 voxels per batch
#define VVEC      (VOX/4)        // float4 elements per batch
#define TEMP      0.2f

// f32 packing: one LDS atomicAdd of (STEP + fg) per voxel.
//   count = round(acc/STEP), sum_fg = acc - STEP*count.
// At gridx=256: ~27648 voxels/block over 189 used bins -> ~146/bin
// (max ~250 at P~1e-9): acc <= ~250*4097 ~ 1.0M << 2^24 -> integer part
// mantissa-exact; sum part (<250) << STEP/2 so round-decode is exact.
// f32 rounding noise ~1e-4 relative on batch-bin means (threshold 1e-2).
#define STEP      4096.0f
#define INV_STEP  (1.0f/4096.0f)

// ---------------------------------------------------------------------------
// Kernel 1: per-batch histogram. ONE packed f32 LDS atomic per voxel
// (ds_add_f32 fast path ~3.3cyc/active-lane-op; R6 showed global atomics are
// ~44Gops/s device-wide — never use them for scatter). KEY: the reference
// drops stub 0 (lab%4==0) and bif 0 (lab<4) — 26.2% of voxels need NO
// histogram update; predicate the atomic so those lanes go inactive.
// fg = softmax(pred, ch)[1] = sigmoid(p1 - p0) since C == 2.
// ---------------------------------------------------------------------------
__global__ __launch_bounds__(256) void histo_kernel(
    const float* __restrict__ pred,     // [B,2,V]
    const float* __restrict__ labmap,   // [B,1,V]
    float* __restrict__ ws_slots)       // [B*gridx][256] packed per-block hist
{
    __shared__ float s_hist[2 * NLAB];  // two copies, lane-parity selected

    const int b = blockIdx.y;
    const int tid = threadIdx.x;

    s_hist[tid] = 0.0f;          // blockDim.x == NLAB == 256
    s_hist[tid + NLAB] = 0.0f;
    __syncthreads();

    const float4* p0 = (const float4*)(pred + (size_t)b * 2 * VOX);
    const float4* p1 = (const float4*)(pred + (size_t)b * 2 * VOX + VOX);
    const float4* lm = (const float4*)(labmap + (size_t)b * VOX);

    const int copy = (tid & 1) << 8;    // 0 or 256: halves same-addr collisions
    const int stride = gridDim.x * 256;
    for (int i = blockIdx.x * 256 + tid; i < VVEC; i += stride) {
        float4 a = p0[i];   // channel 0
        float4 c = p1[i];   // channel 1
        float4 l = lm[i];   // labels (exact integers 0..255 as float)

        float fg0 = 1.0f / (1.0f + __expf(a.x - c.x));
        float fg1 = 1.0f / (1.0f + __expf(a.y - c.y));
        float fg2 = 1.0f / (1.0f + __expf(a.z - c.z));
        float fg3 = 1.0f / (1.0f + __expf(a.w - c.w));

        int l0 = ((int)(l.x + 0.5f)) & (NLAB - 1);
        int l1 = ((int)(l.y + 0.5f)) & (NLAB - 1);
        int l2 = ((int)(l.z + 0.5f)) & (NLAB - 1);
        int l3 = ((int)(l.w + 0.5f)) & (NLAB - 1);

        // Skip labels the loss never reads: stub 0 (lab%4==0) and bif 0
        // (lab<4). ~26.2% of lanes go exec-masked -> fewer atomic lane-ops.
        if ((l0 & 3) && l0 >= 4) atomicAdd(&s_hist[copy + l0], STEP + fg0);
        if ((l1 & 3) && l1 >= 4) atomicAdd(&s_hist[copy + l1], STEP + fg1);
        if ((l2 & 3) && l2 >= 4) atomicAdd(&s_hist[copy + l2], STEP + fg2);
        if ((l3 & 3) && l3 >= 4) atomicAdd(&s_hist[copy + l3], STEP + fg3);
    }
    __syncthreads();

    // Write this block's packed histogram to its private slot (coalesced,
    // unconditional -> no ws zeroing needed).
    ws_slots[((size_t)(b * gridDim.x + blockIdx.x)) * NLAB + tid] =
        s_hist[tid] + s_hist[tid + NLAB];
}

// ---------------------------------------------------------------------------
// Kernel 2: reduce slots (decode packed), then masked softmin -> scalar loss.
// Single block, 1024 threads: thread t handles bin (t&255), slot-quarter
// (t>>8). Reads are coalesced (consecutive bins = consecutive addresses).
// ---------------------------------------------------------------------------
__global__ __launch_bounds__(1024) void finalize_kernel(
    const float* __restrict__ ws_slots, // [B*nslot][256]
    int nslot,
    float* __restrict__ out)            // [1] loss
{
    __shared__ float s_ps[BATCH][4][NLAB];
    __shared__ float s_pc[BATCH][4][NLAB];
    __shared__ float s_fsum[BATCH][NLAB];
    __shared__ float s_fcnt[BATCH][NLAB];

    const int tid  = threadIdx.x;
    const int bin  = tid & (NLAB - 1);
    const int part = tid >> 8;                 // 0..3
    const int per  = (nslot + 3) >> 2;

    for (int b = 0; b < BATCH; ++b) {
        float cs = 0.0f, ss = 0.0f;
        int s0 = part * per;
        int s1 = s0 + per; if (s1 > nslot) s1 = nslot;
        for (int s = s0; s < s1; ++s) {
            float v = ws_slots[((size_t)(b * nslot + s)) * NLAB + bin];
            float c = floorf(v * INV_STEP + 0.5f);   // exact count decode
            cs += c;
            ss += v - c * STEP;                      // packed fg sum
        }
        s_ps[b][part][bin] = ss;
        s_pc[b][part][bin] = cs;
    }
    __syncthreads();

    if (tid < NLAB) {
        for (int b = 0; b < BATCH; ++b) {
            s_fsum[b][tid] = (s_ps[b][0][tid] + s_ps[b][1][tid])
                           + (s_ps[b][2][tid] + s_ps[b][3][tid]);
            s_fcnt[b][tid] = (s_pc[b][0][tid] + s_pc[b][1][tid])
                           + (s_pc[b][2][tid] + s_pc[b][3][tid]);
        }
    }
    __syncthreads();

    if (tid < 64) {
        float total = 0.0f;
        float nbifs = 0.0f;
        if (tid >= 1) {  // bifs 1..63 (reference drops bif 0)
            for (int bb = 0; bb < BATCH; ++bb) {
                float means[3];
                bool  valid[3];
                int   nvalid = 0;
                for (int s = 0; s < 3; ++s) {
                    int lab = tid * 4 + 1 + s;   // stub s+1 (stub 0 dropped)
                    float cnt = s_fcnt[bb][lab];
                    float sum = s_fsum[bb][lab];
                    valid[s] = (cnt >= 1.0f);            // MIN_VOXELS = 1
                    means[s] = sum / fmaxf(cnt, 1.0f);
                    nvalid  += valid[s] ? 1 : 0;
                }
                float logits[3], m = -3e38f;
                for (int s = 0; s < 3; ++s) {
                    logits[s] = valid[s] ? (-means[s] / TEMP) : -1e9f;
                    m = fmaxf(m, logits[s]);
                }
                float e[3], se = 0.0f;
                for (int s = 0; s < 3; ++s) { e[s] = __expf(logits[s] - m); se += e[s]; }
                float score = 0.0f;
                for (int s = 0; s < 3; ++s) {
                    if (valid[s]) score += means[s] * (e[s] / se);
                }
                if (nvalid >= 2) {  // MIN_STUBS = 2
                    total += 1.0f - score;
                    nbifs += 1.0f;
                }
            }
        }
        for (int off = 32; off > 0; off >>= 1) {
            total += __shfl_down(total, off);
            nbifs += __shfl_down(nbifs, off);
        }
        if (tid == 0) {
            out[0] = (nbifs > 0.0f) ? (total / fmaxf(nbifs, 1.0f)) : 0.0f;
        }
    }
}

// ---------------------------------------------------------------------------
extern "C" void kernel_launch(void* const* d_in, const int* in_sizes, int n_in,
                              void* d_out, int out_size, void* d_ws, size_t ws_size,
                              hipStream_t stream) {
    const float* pred = (const float*)d_in[0];   // [B,C,D,H,W] fp32
    const float* lab  = (const float*)d_in[1];   // [B,1,D,H,W] fp32

    // 256 blocks/batch (2 blocks/CU) unless ws is too small for the slots.
    int gridx = 256;
    while ((size_t)gridx * BATCH * NLAB * sizeof(float) > ws_size && gridx > 8)
        gridx >>= 1;

    dim3 grid(gridx, BATCH);
    histo_kernel<<<grid, 256, 0, stream>>>(pred, lab, (float*)d_ws);
    finalize_kernel<<<1, 1024, 0, stream>>>((const float*)d_ws, gridx,
                                            (float*)d_out);
}

// Round 8
// 225.146 us; speedup vs baseline: 1.5610x; 1.0433x over previous
//
#include <hip/hip_runtime.h>
#include <math.h>

// Problem constants (from reference)
#define BATCH     2
#define NLAB      256            // 64 bifs * 4 stubs
#define VOX       (192*192*192)  // 7,077,888 voxels per batch
#define VVEC      (VOX/4)        // float4 elements per batch
#define TEMP      0.2f
#define NPART     16             // reduce parts per batch

// f32 packing: one LDS atomicAdd of (STEP + fg) per voxel.
//   count = round(acc/STEP), sum_fg = acc - STEP*count.
// At gridx=1024: 6912 voxels/block over 189 used bins -> ~37/bin (max ~80
// at P~1e-9): acc <= ~80*4097 ~ 330k << 2^24 -> integer part mantissa-exact,
// count decodes exactly; fg rounding noise ~1e-4 relative on batch-bin means
// (threshold 1e-2; measured absmax 0.0 with this packing at R7).
#define STEP      4096.0f
#define INV_STEP  (1.0f/4096.0f)

// ---------------------------------------------------------------------------
// Kernel 1: per-batch histogram. ONE packed f32 LDS atomic per voxel
// (ds_add_f32 ~1.9-3.3cyc/active-lane-op; global atomics are ~44Gops/s
// device-wide — R6 — never scatter to them). Labels the loss never reads
// (stub 0: lab%4==0; bif 0: lab<4 — 26.2% of voxels) are exec-masked off.
// gridx=1024/batch -> 8 blocks/CU, 32 waves/CU: loads hide behind the
// lane-serial LDS atomic pipe (R7's ~34us base was load-latency exposure
// at 20% occupancy).
// fg = softmax(pred, ch)[1] = sigmoid(p1 - p0) since C == 2.
// ---------------------------------------------------------------------------
__global__ __launch_bounds__(256) void histo_kernel(
    const float* __restrict__ pred,     // [B,2,V]
    const float* __restrict__ labmap,   // [B,1,V]
    float* __restrict__ ws_slots)       // [B*gridx][256] packed per-block hist
{
    __shared__ float s_hist[2 * NLAB];  // two copies, lane-parity selected

    const int b = blockIdx.y;
    const int tid = threadIdx.x;

    s_hist[tid] = 0.0f;          // blockDim.x == NLAB == 256
    s_hist[tid + NLAB] = 0.0f;
    __syncthreads();

    const float4* p0 = (const float4*)(pred + (size_t)b * 2 * VOX);
    const float4* p1 = (const float4*)(pred + (size_t)b * 2 * VOX + VOX);
    const float4* lm = (const float4*)(labmap + (size_t)b * VOX);

    const int copy = (tid & 1) << 8;    // 0 or 256: halves same-addr collisions
    const int stride = gridDim.x * 256;
    for (int i = blockIdx.x * 256 + tid; i < VVEC; i += stride) {
        float4 a = p0[i];   // channel 0
        float4 c = p1[i];   // channel 1
        float4 l = lm[i];   // labels (exact integers 0..255 as float)

        float fg0 = 1.0f / (1.0f + __expf(a.x - c.x));
        float fg1 = 1.0f / (1.0f + __expf(a.y - c.y));
        float fg2 = 1.0f / (1.0f + __expf(a.z - c.z));
        float fg3 = 1.0f / (1.0f + __expf(a.w - c.w));

        int l0 = ((int)(l.x + 0.5f)) & (NLAB - 1);
        int l1 = ((int)(l.y + 0.5f)) & (NLAB - 1);
        int l2 = ((int)(l.z + 0.5f)) & (NLAB - 1);
        int l3 = ((int)(l.w + 0.5f)) & (NLAB - 1);

        if ((l0 & 3) && l0 >= 4) atomicAdd(&s_hist[copy + l0], STEP + fg0);
        if ((l1 & 3) && l1 >= 4) atomicAdd(&s_hist[copy + l1], STEP + fg1);
        if ((l2 & 3) && l2 >= 4) atomicAdd(&s_hist[copy + l2], STEP + fg2);
        if ((l3 & 3) && l3 >= 4) atomicAdd(&s_hist[copy + l3], STEP + fg3);
    }
    __syncthreads();

    // Write this block's packed histogram to its private slot (coalesced,
    // unconditional -> no ws zeroing needed).
    ws_slots[((size_t)(b * gridDim.x + blockIdx.x)) * NLAB + tid] =
        s_hist[tid] + s_hist[tid + NLAB];
}

// ---------------------------------------------------------------------------
// Kernel 2: parallel slot reduction. Block r: batch = r/NPART, part =
// r%NPART; 256 threads = bins. Each block decodes+sums nslot/NPART slots
// (coalesced 1KB rows) into partial [B*NPART][256] sum/cnt arrays.
// ---------------------------------------------------------------------------
__global__ __launch_bounds__(256) void reduce_kernel(
    const float* __restrict__ ws_slots, // [B*nslot][256]
    int nslot,
    float* __restrict__ psum,           // [B*NPART][256]
    float* __restrict__ pcnt)           // [B*NPART][256]
{
    const int bin  = threadIdx.x;
    const int b    = blockIdx.x / NPART;
    const int part = blockIdx.x % NPART;
    const int per  = nslot / NPART;

    float cs = 0.0f, ss = 0.0f;
    for (int s = part * per; s < (part + 1) * per; ++s) {
        float v = ws_slots[((size_t)(b * nslot + s)) * NLAB + bin];
        float c = floorf(v * INV_STEP + 0.5f);   // exact count decode
        cs += c;
        ss += v - c * STEP;                      // packed fg sum
    }
    psum[(size_t)blockIdx.x * NLAB + bin] = ss;
    pcnt[(size_t)blockIdx.x * NLAB + bin] = cs;
}

// ---------------------------------------------------------------------------
// Kernel 3: fold partials, then masked softmin -> scalar loss.
// ---------------------------------------------------------------------------
__global__ __launch_bounds__(256) void scalar_kernel(
    const float* __restrict__ psum,     // [B*NPART][256]
    const float* __restrict__ pcnt,
    float* __restrict__ out)            // [1] loss
{
    __shared__ float s_fsum[BATCH][NLAB];
    __shared__ float s_fcnt[BATCH][NLAB];

    const int tid = threadIdx.x;        // 256 threads = bins

    for (int b = 0; b < BATCH; ++b) {
        float ss = 0.0f, cs = 0.0f;
        for (int p = 0; p < NPART; ++p) {
            ss += psum[(size_t)(b * NPART + p) * NLAB + tid];
            cs += pcnt[(size_t)(b * NPART + p) * NLAB + tid];
        }
        s_fsum[b][tid] = ss;
        s_fcnt[b][tid] = cs;
    }
    __syncthreads();

    if (tid < 64) {
        float total = 0.0f;
        float nbifs = 0.0f;
        if (tid >= 1) {  // bifs 1..63 (reference drops bif 0)
            for (int bb = 0; bb < BATCH; ++bb) {
                float means[3];
                bool  valid[3];
                int   nvalid = 0;
                for (int s = 0; s < 3; ++s) {
                    int lab = tid * 4 + 1 + s;   // stub s+1 (stub 0 dropped)
                    float cnt = s_fcnt[bb][lab];
                    float sum = s_fsum[bb][lab];
                    valid[s] = (cnt >= 1.0f);            // MIN_VOXELS = 1
                    means[s] = sum / fmaxf(cnt, 1.0f);
                    nvalid  += valid[s] ? 1 : 0;
                }
                float logits[3], m = -3e38f;
                for (int s = 0; s < 3; ++s) {
                    logits[s] = valid[s] ? (-means[s] / TEMP) : -1e9f;
                    m = fmaxf(m, logits[s]);
                }
                float e[3], se = 0.0f;
                for (int s = 0; s < 3; ++s) { e[s] = __expf(logits[s] - m); se += e[s]; }
                float score = 0.0f;
                for (int s = 0; s < 3; ++s) {
                    if (valid[s]) score += means[s] * (e[s] / se);
                }
                if (nvalid >= 2) {  // MIN_STUBS = 2
                    total += 1.0f - score;
                    nbifs += 1.0f;
                }
            }
        }
        for (int off = 32; off > 0; off >>= 1) {
            total += __shfl_down(total, off);
            nbifs += __shfl_down(nbifs, off);
        }
        if (tid == 0) {
            out[0] = (nbifs > 0.0f) ? (total / fmaxf(nbifs, 1.0f)) : 0.0f;
        }
    }
}

// ---------------------------------------------------------------------------
extern "C" void kernel_launch(void* const* d_in, const int* in_sizes, int n_in,
                              void* d_out, int out_size, void* d_ws, size_t ws_size,
                              hipStream_t stream) {
    const float* pred = (const float*)d_in[0];   // [B,C,D,H,W] fp32
    const float* lab  = (const float*)d_in[1];   // [B,1,D,H,W] fp32

    // 1024 blocks/batch (8 blocks/CU, full wave occupancy); degrade if ws
    // can't hold the slots + partials.
    int gridx = 1024;
    while (((size_t)gridx * BATCH * NLAB + 2u * BATCH * NPART * NLAB) * sizeof(float)
               > ws_size && gridx > NPART)
        gridx >>= 1;

    float* ws_slots = (float*)d_ws;                          // [B*gridx][256]
    float* psum = ws_slots + (size_t)BATCH * gridx * NLAB;   // [B*NPART][256]
    float* pcnt = psum + (size_t)BATCH * NPART * NLAB;       // [B*NPART][256]

    dim3 grid(gridx, BATCH);
    histo_kernel<<<grid, 256, 0, stream>>>(pred, lab, ws_slots);
    reduce_kernel<<<BATCH * NPART, 256, 0, stream>>>(ws_slots, gridx, psum, pcnt);
    scalar_kernel<<<1, 256, 0, stream>>>(psum, pcnt, (float*)d_out);
}

// Round 9
// 205.970 us; speedup vs baseline: 1.7063x; 1.0931x over previous
//
#include <hip/hip_runtime.h>
#include <math.h>

// Problem constants (from reference)
#define BATCH     2
#define NLAB      256            // 64 bifs * 4 stubs
#define VOX       (192*192*192)  // 7,077,888 voxels per batch
#define VVEC      (VOX/4)        // float4 elements per batch
#define TEMP      0.2f
#define GRIDX     256            // blocks per batch (2 blocks/CU — R7/R8 A/B:
                                 // MORE blocks/CU slows the DS-atomic pipe)
#define NITER     (VVEC/(GRIDX*256))  // = 27, exact (compile-time trip count)
#define NPART     16             // reduce parts per batch

// f32 packing: one LDS atomicAdd of (STEP + fg) per voxel.
//   count = round(acc/STEP), sum_fg = acc - STEP*count.
// At GRIDX=256: ~27648 voxels/block over 189 used bins -> ~146/bin
// (max ~250 at P~1e-9): acc <= ~250*4097 ~ 1.0M << 2^24 -> integer part
// mantissa-exact, count decodes exactly; fg rounding noise ~1e-4 relative
// on batch-bin means (threshold 1e-2; measured absmax 0.0 at R7 with this).
#define STEP      4096.0f
#define INV_STEP  (1.0f/4096.0f)

// ---------------------------------------------------------------------------
// Kernel 1: per-batch histogram. ONE packed f32 LDS atomic per voxel.
// Calibrated pipe model (R1/R5/R7/R8): ds_add_f32 is lane-serial
// ~3.3cyc/active-lane-op, independent of address distribution and of
// occupancy (R8: 62% occ was SLOWER than R7's 20%). Global atomics are
// ~44Gops/s device-wide (R6) — never scatter to them. Labels the loss never
// reads (stub 0: lab%4==0; bif 0: lab<4 — 26.2% of voxels) are exec-masked.
// fg = softmax(pred, ch)[1] = sigmoid(p1 - p0) since C == 2.
// ---------------------------------------------------------------------------
__global__ __launch_bounds__(256) void histo_kernel(
    const float* __restrict__ pred,     // [B,2,V]
    const float* __restrict__ labmap,   // [B,1,V]
    float* __restrict__ ws_slots)       // [B*GRIDX][256] packed per-block hist
{
    __shared__ float s_hist[2 * NLAB];  // two copies, lane-parity selected

    const int b = blockIdx.y;
    const int tid = threadIdx.x;

    s_hist[tid] = 0.0f;          // blockDim.x == NLAB == 256
    s_hist[tid + NLAB] = 0.0f;
    __syncthreads();

    const float4* p0 = (const float4*)(pred + (size_t)b * 2 * VOX);
    const float4* p1 = (const float4*)(pred + (size_t)b * 2 * VOX + VOX);
    const float4* lm = (const float4*)(labmap + (size_t)b * VOX);

    const int copy = (tid & 1) << 8;    // 0 or 256: halves same-addr collisions
    const int base = blockIdx.x * 256 + tid;

    // Compile-time trip count (27) + unroll: deeper outstanding loads (ILP)
    // to cover VMEM latency at 2 blocks/CU — TLP doesn't help (R8).
    #pragma unroll 3
    for (int it = 0; it < NITER; ++it) {
        const int i = base + it * (GRIDX * 256);
        float4 a = p0[i];   // channel 0
        float4 c = p1[i];   // channel 1
        float4 l = lm[i];   // labels (exact integers 0..255 as float)

        float fg0 = 1.0f / (1.0f + __expf(a.x - c.x));
        float fg1 = 1.0f / (1.0f + __expf(a.y - c.y));
        float fg2 = 1.0f / (1.0f + __expf(a.z - c.z));
        float fg3 = 1.0f / (1.0f + __expf(a.w - c.w));

        int l0 = ((int)(l.x + 0.5f)) & (NLAB - 1);
        int l1 = ((int)(l.y + 0.5f)) & (NLAB - 1);
        int l2 = ((int)(l.z + 0.5f)) & (NLAB - 1);
        int l3 = ((int)(l.w + 0.5f)) & (NLAB - 1);

        if ((l0 & 3) && l0 >= 4) atomicAdd(&s_hist[copy + l0], STEP + fg0);
        if ((l1 & 3) && l1 >= 4) atomicAdd(&s_hist[copy + l1], STEP + fg1);
        if ((l2 & 3) && l2 >= 4) atomicAdd(&s_hist[copy + l2], STEP + fg2);
        if ((l3 & 3) && l3 >= 4) atomicAdd(&s_hist[copy + l3], STEP + fg3);
    }
    __syncthreads();

    // Write this block's packed histogram to its private slot (coalesced,
    // unconditional -> no ws zeroing needed).
    ws_slots[((size_t)(b * GRIDX + blockIdx.x)) * NLAB + tid] =
        s_hist[tid] + s_hist[tid + NLAB];
}

// ---------------------------------------------------------------------------
// Kernel 2: parallel slot reduction (R8 structure — saved ~14us vs a
// single-block finalize). Block r: batch = r/NPART, part = r%NPART; 256
// threads = bins. Decode + sum GRIDX/NPART slots (coalesced 1KB rows).
// ---------------------------------------------------------------------------
__global__ __launch_bounds__(256) void reduce_kernel(
    const float* __restrict__ ws_slots, // [B*GRIDX][256]
    float* __restrict__ psum,           // [B*NPART][256]
    float* __restrict__ pcnt)           // [B*NPART][256]
{
    const int bin  = threadIdx.x;
    const int b    = blockIdx.x / NPART;
    const int part = blockIdx.x % NPART;
    const int per  = GRIDX / NPART;

    float cs = 0.0f, ss = 0.0f;
    for (int s = part * per; s < (part + 1) * per; ++s) {
        float v = ws_slots[((size_t)(b * GRIDX + s)) * NLAB + bin];
        float c = floorf(v * INV_STEP + 0.5f);   // exact count decode
        cs += c;
        ss += v - c * STEP;                      // packed fg sum
    }
    psum[(size_t)blockIdx.x * NLAB + bin] = ss;
    pcnt[(size_t)blockIdx.x * NLAB + bin] = cs;
}

// ---------------------------------------------------------------------------
// Kernel 3: fold partials, then masked softmin -> scalar loss.
// ---------------------------------------------------------------------------
__global__ __launch_bounds__(256) void scalar_kernel(
    const float* __restrict__ psum,     // [B*NPART][256]
    const float* __restrict__ pcnt,
    float* __restrict__ out)            // [1] loss
{
    __shared__ float s_fsum[BATCH][NLAB];
    __shared__ float s_fcnt[BATCH][NLAB];

    const int tid = threadIdx.x;        // 256 threads = bins

    for (int b = 0; b < BATCH; ++b) {
        float ss = 0.0f, cs = 0.0f;
        for (int p = 0; p < NPART; ++p) {
            ss += psum[(size_t)(b * NPART + p) * NLAB + tid];
            cs += pcnt[(size_t)(b * NPART + p) * NLAB + tid];
        }
        s_fsum[b][tid] = ss;
        s_fcnt[b][tid] = cs;
    }
    __syncthreads();

    if (tid < 64) {
        float total = 0.0f;
        float nbifs = 0.0f;
        if (tid >= 1) {  // bifs 1..63 (reference drops bif 0)
            for (int bb = 0; bb < BATCH; ++bb) {
                float means[3];
                bool  valid[3];
                int   nvalid = 0;
                for (int s = 0; s < 3; ++s) {
                    int lab = tid * 4 + 1 + s;   // stub s+1 (stub 0 dropped)
                    float cnt = s_fcnt[bb][lab];
                    float sum = s_fsum[bb][lab];
                    valid[s] = (cnt >= 1.0f);            // MIN_VOXELS = 1
                    means[s] = sum / fmaxf(cnt, 1.0f);
                    nvalid  += valid[s] ? 1 : 0;
                }
                float logits[3], m = -3e38f;
                for (int s = 0; s < 3; ++s) {
                    logits[s] = valid[s] ? (-means[s] / TEMP) : -1e9f;
                    m = fmaxf(m, logits[s]);
                }
                float e[3], se = 0.0f;
                for (int s = 0; s < 3; ++s) { e[s] = __expf(logits[s] - m); se += e[s]; }
                float score = 0.0f;
                for (int s = 0; s < 3; ++s) {
                    if (valid[s]) score += means[s] * (e[s] / se);
                }
                if (nvalid >= 2) {  // MIN_STUBS = 2
                    total += 1.0f - score;
                    nbifs += 1.0f;
                }
            }
        }
        for (int off = 32; off > 0; off >>= 1) {
            total += __shfl_down(total, off);
            nbifs += __shfl_down(nbifs, off);
        }
        if (tid == 0) {
            out[0] = (nbifs > 0.0f) ? (total / fmaxf(nbifs, 1.0f)) : 0.0f;
        }
    }
}

// ---------------------------------------------------------------------------
extern "C" void kernel_launch(void* const* d_in, const int* in_sizes, int n_in,
                              void* d_out, int out_size, void* d_ws, size_t ws_size,
                              hipStream_t stream) {
    const float* pred = (const float*)d_in[0];   // [B,C,D,H,W] fp32
    const float* lab  = (const float*)d_in[1];   // [B,1,D,H,W] fp32

    float* ws_slots = (float*)d_ws;                          // [B*GRIDX][256]
    float* psum = ws_slots + (size_t)BATCH * GRIDX * NLAB;   // [B*NPART][256]
    float* pcnt = psum + (size_t)BATCH * NPART * NLAB;       // [B*NPART][256]

    dim3 grid(GRIDX, BATCH);
    histo_kernel<<<grid, 256, 0, stream>>>(pred, lab, ws_slots);
    reduce_kernel<<<BATCH * NPART, 256, 0, stream>>>(ws_slots, psum, pcnt);
    scalar_kernel<<<1, 256, 0, stream>>>(psum, pcnt, (float*)d_out);
}